// Round 11
// baseline (201.430 us; speedup 1.0000x reference)
//
#include <hip/hip_runtime.h>
#include <hip/hip_bf16.h>
#include <math.h>

// B=2, T=2048, D=1024, H=16, hd=64. fp32 in/out.
// Round 11: barrier amortization. (1) QKV merged into one kernel: 128x64
// tiles, A staged once per k-iter for all three weights (24 MFMA + 10 b128
// per wave-interval vs 16+8). (2) attn stages 2 k-tiles per barrier pair
// (KT=128, 41.2 KB LDS, 3 blocks/CU cap). Rest as R10.
// ws (MB): xb@0[8] Wqt@8[2] Wkt@10[2] Wvt@12[2] Wot@14[2]
// Qb@16[8] Kb@24[8] VbT@32[8] Yb@40[8] = 48 MB.

#define Bsz  2
#define Tseq 2048
#define Dm   1024
#define NH   16
#define HD   64

typedef short bf16x8 __attribute__((ext_vector_type(8)));
typedef float floatx4 __attribute__((ext_vector_type(4)));

__device__ __forceinline__ unsigned short f2bf(float f) {
    __hip_bfloat16 h = __float2bfloat16(f);
    return *reinterpret_cast<unsigned short*>(&h);
}

// cheap bf16: round-half-up (max 0.5 ulp); 2 VALU ops
__device__ __forceinline__ unsigned short f2bf_fast(float f) {
    unsigned int u = __builtin_bit_cast(unsigned int, f);
    return (unsigned short)((u + 0x8000u) >> 16);
}

// async global->LDS, 16 B per lane. LDS dest must be waveBase + lane*16.
__device__ __forceinline__ void lds16(unsigned short* lds, const unsigned short* g) {
    __builtin_amdgcn_global_load_lds(
        (const __attribute__((address_space(1))) void*)g,
        (__attribute__((address_space(3))) void*)lds, 16, 0, 0);
}

// ---------------- prep: W transpose-cast (z<4) + x cast (z>=4) ---------------
__global__ __launch_bounds__(256) void prep(const float* __restrict__ x,
                                            const float* __restrict__ W0,
                                            const float* __restrict__ W1,
                                            const float* __restrict__ W2,
                                            const float* __restrict__ W3,
                                            unsigned short* __restrict__ xb,
                                            unsigned short* __restrict__ T0,
                                            unsigned short* __restrict__ T1,
                                            unsigned short* __restrict__ T2,
                                            unsigned short* __restrict__ T3) {
    __shared__ float t[64][65];
    const int z = blockIdx.z;
    if (z >= 4) {  // cast x
        const int bi = (z - 4) * 256 + blockIdx.y * 16 + blockIdx.x;
        const size_t i = (size_t)bi * 256 + threadIdx.x;
        const float4 v = ((const float4*)x)[i];
        ushort4 o;
        o.x = f2bf(v.x); o.y = f2bf(v.y); o.z = f2bf(v.z); o.w = f2bf(v.w);
        ((ushort4*)xb)[i] = o;
        return;
    }
    const float* W = (z == 0) ? W0 : (z == 1) ? W1 : (z == 2) ? W2 : W3;
    unsigned short* T = (z == 0) ? T0 : (z == 1) ? T1 : (z == 2) ? T2 : T3;
    const int k0 = blockIdx.y * 64, n0 = blockIdx.x * 64;
    const int row = threadIdx.x >> 6, col = threadIdx.x & 63;
#pragma unroll
    for (int p = 0; p < 16; ++p)
        t[p * 4 + row][col] = W[(size_t)(k0 + p * 4 + row) * Dm + n0 + col];
    __syncthreads();
#pragma unroll
    for (int p = 0; p < 16; ++p)
        T[(size_t)(n0 + p * 4 + row) * Dm + k0 + col] = f2bf(t[col][p * 4 + row]);
}

// -------- merged QKV GEMM: 128(M)x64(N) tile, all three weights per block ----
// A-tile staged once per k-iter; 3 B-tiles staged alongside. Per wave per
// interval: 24 MFMA, 10 b128 frag reads. Q scaled 0.125*log2e (exp2 softmax).
// V output written transposed into VbT [bh][d][tok] (frag rows = 4 consecutive
// tokens -> ushort4).
__global__ __launch_bounds__(256) void gemm_qkv(const unsigned short* __restrict__ xb,
                                                const unsigned short* __restrict__ Wqt,
                                                const unsigned short* __restrict__ Wkt,
                                                const unsigned short* __restrict__ Wvt,
                                                unsigned short* __restrict__ Qb,
                                                unsigned short* __restrict__ Kb,
                                                unsigned short* __restrict__ VbT) {
    __shared__ unsigned short As[128 * 32];
    __shared__ unsigned short Bs[3][64 * 32];
    const int m0 = blockIdx.y * 128, n0 = blockIdx.x * 64;
    const int tid = threadIdx.x;
    const int lane = tid & 63, wave = tid >> 6;
    const int l15 = lane & 15, quad = lane >> 4;
    const int wm = (wave >> 1) * 64, wn = (wave & 1) * 32;

    const unsigned short* Wt[3] = {Wqt, Wkt, Wvt};

    floatx4 acc[3][4][2];
#pragma unroll
    for (int zz = 0; zz < 3; ++zz)
#pragma unroll
        for (int i = 0; i < 4; ++i)
#pragma unroll
            for (int j = 0; j < 2; ++j) acc[zz][i][j] = (floatx4){0.f, 0.f, 0.f, 0.f};

    const int arow0 = tid >> 2;            // 0..63 (A rows covered twice)
    const int kc = (tid & 3) * 8;

    for (int k0 = 0; k0 < Dm; k0 += 32) {
        __syncthreads();
#pragma unroll
        for (int c = 0; c < 2; ++c) {
            const int row = c * 64 + arow0;
            lds16(&As[row * 32 + kc], xb + (size_t)(m0 + row) * Dm + k0 + kc);
        }
#pragma unroll
        for (int zz = 0; zz < 3; ++zz)
            lds16(&Bs[zz][arow0 * 32 + kc], Wt[zz] + (size_t)(n0 + arow0) * Dm + k0 + kc);
        __syncthreads();

        bf16x8 af[4];
#pragma unroll
        for (int i = 0; i < 4; ++i)
            af[i] = *(const bf16x8*)&As[(wm + i * 16 + l15) * 32 + quad * 8];
#pragma unroll
        for (int zz = 0; zz < 3; ++zz) {
            bf16x8 bf[2];
#pragma unroll
            for (int j = 0; j < 2; ++j)
                bf[j] = *(const bf16x8*)&Bs[zz][(wn + j * 16 + l15) * 32 + quad * 8];
#pragma unroll
            for (int i = 0; i < 4; ++i)
#pragma unroll
                for (int j = 0; j < 2; ++j)
                    acc[zz][i][j] = __builtin_amdgcn_mfma_f32_16x16x32_bf16(af[i], bf[j], acc[zz][i][j], 0, 0, 0);
        }
    }

    // epilogues
    const float qscale = 0.125f * 1.4426950408889634f;
#pragma unroll
    for (int zz = 0; zz < 2; ++zz) {   // Q (scaled), K
        unsigned short* C = (zz == 0) ? Qb : Kb;
        const float sc = (zz == 0) ? qscale : 1.0f;
#pragma unroll
        for (int i = 0; i < 4; ++i)
#pragma unroll
            for (int j = 0; j < 2; ++j)
#pragma unroll
                for (int r = 0; r < 4; ++r) {
                    const int row = m0 + wm + i * 16 + quad * 4 + r;
                    const int col = n0 + wn + j * 16 + l15;
                    C[(size_t)row * Dm + col] = f2bf(acc[zz][i][j][r] * sc);
                }
    }
    // V -> VbT transposed
#pragma unroll
    for (int i = 0; i < 4; ++i)
#pragma unroll
        for (int j = 0; j < 2; ++j) {
            const int col = n0 + wn + j * 16 + l15;
            const int hh = col >> 6, dd = col & 63;
            const int tok = m0 + wm + i * 16 + quad * 4;
            const int bb = tok >> 11, tl = tok & (Tseq - 1);
            ushort4 o;
            o.x = f2bf(acc[2][i][j][0]); o.y = f2bf(acc[2][i][j][1]);
            o.z = f2bf(acc[2][i][j][2]); o.w = f2bf(acc[2][i][j][3]);
            *(ushort4*)&VbT[((size_t)((bb * NH + hh) * HD + dd)) * Tseq + tl] = o;
        }
}

// Final GEMM: Yb @ Wo -> fp32 out. 128(M)x64(N) tiles -> 512 blocks (2/CU).
__global__ __launch_bounds__(256) void gemm_out(const unsigned short* __restrict__ Yb,
                                                const unsigned short* __restrict__ Wot,
                                                float* __restrict__ out) {
    __shared__ unsigned short As[128 * 32];
    __shared__ unsigned short Bs[64 * 32];
    const int m0 = blockIdx.y * 128, n0 = blockIdx.x * 64;
    const int tid = threadIdx.x;
    const int lane = tid & 63, wave = tid >> 6;
    const int l15 = lane & 15, quad = lane >> 4;
    const int wm = (wave >> 1) * 64, wn = (wave & 1) * 32;

    floatx4 acc[4][2];
#pragma unroll
    for (int i = 0; i < 4; ++i)
#pragma unroll
        for (int j = 0; j < 2; ++j) acc[i][j] = (floatx4){0.f, 0.f, 0.f, 0.f};

    for (int k0 = 0; k0 < Dm; k0 += 32) {
        __syncthreads();
        {
#pragma unroll
            for (int c = 0; c < 2; ++c) {
                const int idx = c * 256 + tid;
                const int row = idx >> 2, kc = (idx & 3) * 8;
                lds16(&As[row * 32 + kc], Yb + (size_t)(m0 + row) * Dm + k0 + kc);
            }
            const int row = tid >> 2, kc = (tid & 3) * 8;
            lds16(&Bs[row * 32 + kc], Wot + (size_t)(n0 + row) * Dm + k0 + kc);
        }
        __syncthreads();
        bf16x8 af[4], bf[2];
#pragma unroll
        for (int i = 0; i < 4; ++i)
            af[i] = *(const bf16x8*)&As[(wm + i * 16 + l15) * 32 + quad * 8];
#pragma unroll
        for (int j = 0; j < 2; ++j)
            bf[j] = *(const bf16x8*)&Bs[(wn + j * 16 + l15) * 32 + quad * 8];
#pragma unroll
        for (int i = 0; i < 4; ++i)
#pragma unroll
            for (int j = 0; j < 2; ++j)
                acc[i][j] = __builtin_amdgcn_mfma_f32_16x16x32_bf16(af[i], bf[j], acc[i][j], 0, 0, 0);
    }

#pragma unroll
    for (int i = 0; i < 4; ++i)
#pragma unroll
        for (int j = 0; j < 2; ++j)
#pragma unroll
            for (int r = 0; r < 4; ++r) {
                const int row = m0 + wm + i * 16 + quad * 4 + r;
                const int col = n0 + wn + j * 16 + l15;
                out[(size_t)row * Dm + col] = acc[i][j][r];
            }
}

// ------------------------- bf16 MFMA causal flash attention -------------------
// grid (B*NH=32, 32). qt = 31 - blockIdx.y (longest blocks dispatch first).
// KT=128: two 64-key sub-tiles staged per barrier pair (half the barriers).
// 16 q/wave, 64B-row half-tiles, fixed-max exp2 softmax, l in epilogue.
__global__ __launch_bounds__(256) void attn_mfma(const unsigned short* __restrict__ Qb,
                                                 const unsigned short* __restrict__ Kb,
                                                 const unsigned short* __restrict__ VbT,
                                                 unsigned short* __restrict__ Yb) {
    const int bh = blockIdx.x;
    const int b = bh >> 4;
    const int h = bh & 15;
    const int qt = 31 - blockIdx.y;
    const int tid = threadIdx.x;
    const int wave = tid >> 6;
    const int lane = tid & 63;
    const int l15 = lane & 15;
    const int quad = lane >> 4;

    __shared__ unsigned short Ks0[2][64][32];  // [sub][key][d 0..31]
    __shared__ unsigned short Ks1[2][64][32];  // [sub][key][d 32..63]
    __shared__ unsigned short Vt0[2][64][32];  // [sub][d][key 0..31]
    __shared__ unsigned short Vt1[2][64][32];  // [sub][d][key 32..63]
    __shared__ unsigned short Ps[4][16][72];   // per-wave P transpose (16B rows)

    const size_t tok0 = (size_t)b * Tseq;
    const int colh = h * HD;
    const unsigned short* vbase = VbT + (size_t)bh * HD * Tseq;

    const int qrow = qt * 64 + wave * 16;

    const unsigned short* qptr = Qb + (tok0 + qrow + l15) * Dm + colh + quad * 8;
    const bf16x8 qf0 = *(const bf16x8*)(qptr);
    const bf16x8 qf1 = *(const bf16x8*)(qptr + 32);

    float l_lane[4] = {0.f, 0.f, 0.f, 0.f};
    floatx4 o_acc[4];
#pragma unroll
    for (int t = 0; t < 4; ++t) o_acc[t] = (floatx4){0.f, 0.f, 0.f, 0.f};

    const int srow = tid >> 2;
    const int sc8 = (tid & 3) * 8;

    const int niter = (qt + 2) >> 1;   // ceil((qt+1)/2), 64-key tiles in pairs
    for (int it = 0; it < niter; ++it) {
        const int k0 = it * 128;
        __syncthreads();
#pragma unroll
        for (int s = 0; s < 2; ++s) {
            const unsigned short* krow = Kb + (tok0 + k0 + s * 64 + srow) * Dm + colh;
            const unsigned short* vrow = vbase + (size_t)srow * Tseq + k0 + s * 64;
            lds16(&Ks0[s][srow][sc8], krow + sc8);
            lds16(&Ks1[s][srow][sc8], krow + 32 + sc8);
            lds16(&Vt0[s][srow][sc8], vrow + sc8);
            lds16(&Vt1[s][srow][sc8], vrow + 32 + sc8);
        }
        __syncthreads();

#pragma unroll
        for (int s = 0; s < 2; ++s) {
            const int k0s = k0 + s * 64;
            if (k0s > qrow + 15) continue;  // wave-uniform; no barriers inside

            floatx4 sf[4];
#pragma unroll
            for (int t = 0; t < 4; ++t) {
                floatx4 c = (floatx4){0.f, 0.f, 0.f, 0.f};
                const bf16x8 b0 = *(const bf16x8*)&Ks0[s][t * 16 + l15][quad * 8];
                const bf16x8 b1 = *(const bf16x8*)&Ks1[s][t * 16 + l15][quad * 8];
                c = __builtin_amdgcn_mfma_f32_16x16x32_bf16(qf0, b0, c, 0, 0, 0);
                c = __builtin_amdgcn_mfma_f32_16x16x32_bf16(qf1, b1, c, 0, 0, 0);
                sf[t] = c;
            }

            if (k0s + 63 > qrow) {  // diagonal sub-tile: causal mask
#pragma unroll
                for (int t = 0; t < 4; ++t)
#pragma unroll
                    for (int r = 0; r < 4; ++r) {
                        const int kl = k0s + t * 16 + l15;
                        const int ql = qrow + quad * 4 + r;
                        if (kl > ql) sf[t][r] = -1.0e30f;
                    }
            }

#pragma unroll
            for (int t = 0; t < 4; ++t)
#pragma unroll
                for (int r = 0; r < 4; ++r) {
                    const float p = __builtin_amdgcn_exp2f(sf[t][r]);
                    l_lane[r] += p;
                    Ps[wave][quad * 4 + r][t * 16 + l15] = f2bf_fast(p);
                }

            const bf16x8 pa0 = *(const bf16x8*)&Ps[wave][l15][quad * 8];
            const bf16x8 pa1 = *(const bf16x8*)&Ps[wave][l15][32 + quad * 8];
#pragma unroll
            for (int t = 0; t < 4; ++t) {
                const bf16x8 vb0 = *(const bf16x8*)&Vt0[s][t * 16 + l15][quad * 8];
                const bf16x8 vb1 = *(const bf16x8*)&Vt1[s][t * 16 + l15][quad * 8];
                o_acc[t] = __builtin_amdgcn_mfma_f32_16x16x32_bf16(pa0, vb0, o_acc[t], 0, 0, 0);
                o_acc[t] = __builtin_amdgcn_mfma_f32_16x16x32_bf16(pa1, vb1, o_acc[t], 0, 0, 0);
            }
        }
    }

#pragma unroll
    for (int off = 1; off < 16; off <<= 1)
#pragma unroll
        for (int r = 0; r < 4; ++r)
            l_lane[r] += __shfl_xor(l_lane[r], off);
    float inv_l[4];
#pragma unroll
    for (int r = 0; r < 4; ++r) inv_l[r] = 1.0f / l_lane[r];
#pragma unroll
    for (int t = 0; t < 4; ++t)
#pragma unroll
        for (int r = 0; r < 4; ++r) {
            const int q = qrow + quad * 4 + r;
            Yb[(tok0 + q) * Dm + colh + t * 16 + l15] = f2bf(o_acc[t][r] * inv_l[r]);
        }
}

// ------------------------------- launch --------------------------------------
extern "C" void kernel_launch(void* const* d_in, const int* in_sizes, int n_in,
                              void* d_out, int out_size, void* d_ws, size_t ws_size,
                              hipStream_t stream) {
    const float* x  = (const float*)d_in[0];
    const float* Wq = (const float*)d_in[1];
    const float* Wk = (const float*)d_in[2];
    const float* Wv = (const float*)d_in[3];
    const float* Wo = (const float*)d_in[4];
    float* out = (float*)d_out;

    const int M = Bsz * Tseq;  // 4096
    char* ws = (char*)d_ws;
    unsigned short* xb  = (unsigned short*)(ws);
    unsigned short* Wqt = (unsigned short*)(ws + (((size_t)8)  << 20));
    unsigned short* Wkt = (unsigned short*)(ws + (((size_t)10) << 20));
    unsigned short* Wvt = (unsigned short*)(ws + (((size_t)12) << 20));
    unsigned short* Wot = (unsigned short*)(ws + (((size_t)14) << 20));
    unsigned short* Qb  = (unsigned short*)(ws + (((size_t)16) << 20));
    unsigned short* Kb  = (unsigned short*)(ws + (((size_t)24) << 20));
    unsigned short* VbT = (unsigned short*)(ws + (((size_t)32) << 20));
    unsigned short* Yb  = (unsigned short*)(ws + (((size_t)40) << 20));

    dim3 blk(256);
    hipLaunchKernelGGL(prep, dim3(16, 16, 20), blk, 0, stream,
                       x, Wq, Wk, Wv, Wo, xb, Wqt, Wkt, Wvt, Wot);

    hipLaunchKernelGGL(gemm_qkv, dim3(Dm / 64, M / 128), blk, 0, stream,
                       xb, Wqt, Wkt, Wvt, Qb, Kb, VbT);

    hipLaunchKernelGGL(attn_mfma, dim3(Bsz * NH, 32), blk, 0, stream, Qb, Kb, VbT, Yb);

    hipLaunchKernelGGL(gemm_out, dim3(Dm / 64, M / 128), blk, 0, stream, Yb, Wot, out);
}

// Round 12
// 173.662 us; speedup vs baseline: 1.1599x; 1.1599x over previous
//
#include <hip/hip_runtime.h>
#include <hip/hip_bf16.h>
#include <math.h>

// B=2, T=2048, D=1024, H=16, hd=64. fp32 in/out.
// Round 12: revert gemm_qkv to R10 split form (768 blocks = 3/CU; merged
// 512-block version regressed: 2 blocks/CU can't hide barrier drains —
// same lesson as R9). Keep attn KT=128 from R11 to resolve its effect.
// ws (MB): xb@0[8] Wqt@8[2] Wkt@10[2] Wvt@12[2] Wot@14[2]
// Qb@16[8] Kb@24[8] VbT@32[8] Yb@40[8] = 48 MB.

#define Bsz  2
#define Tseq 2048
#define Dm   1024
#define NH   16
#define HD   64

typedef short bf16x8 __attribute__((ext_vector_type(8)));
typedef float floatx4 __attribute__((ext_vector_type(4)));

__device__ __forceinline__ unsigned short f2bf(float f) {
    __hip_bfloat16 h = __float2bfloat16(f);
    return *reinterpret_cast<unsigned short*>(&h);
}

// cheap bf16: round-half-up (max 0.5 ulp); 2 VALU ops
__device__ __forceinline__ unsigned short f2bf_fast(float f) {
    unsigned int u = __builtin_bit_cast(unsigned int, f);
    return (unsigned short)((u + 0x8000u) >> 16);
}

// async global->LDS, 16 B per lane. LDS dest must be waveBase + lane*16.
__device__ __forceinline__ void lds16(unsigned short* lds, const unsigned short* g) {
    __builtin_amdgcn_global_load_lds(
        (const __attribute__((address_space(1))) void*)g,
        (__attribute__((address_space(3))) void*)lds, 16, 0, 0);
}

// ---------------- prep: W transpose-cast (z<4) + x cast (z>=4) ---------------
__global__ __launch_bounds__(256) void prep(const float* __restrict__ x,
                                            const float* __restrict__ W0,
                                            const float* __restrict__ W1,
                                            const float* __restrict__ W2,
                                            const float* __restrict__ W3,
                                            unsigned short* __restrict__ xb,
                                            unsigned short* __restrict__ T0,
                                            unsigned short* __restrict__ T1,
                                            unsigned short* __restrict__ T2,
                                            unsigned short* __restrict__ T3) {
    __shared__ float t[64][65];
    const int z = blockIdx.z;
    if (z >= 4) {  // cast x
        const int bi = (z - 4) * 256 + blockIdx.y * 16 + blockIdx.x;
        const size_t i = (size_t)bi * 256 + threadIdx.x;
        const float4 v = ((const float4*)x)[i];
        ushort4 o;
        o.x = f2bf(v.x); o.y = f2bf(v.y); o.z = f2bf(v.z); o.w = f2bf(v.w);
        ((ushort4*)xb)[i] = o;
        return;
    }
    const float* W = (z == 0) ? W0 : (z == 1) ? W1 : (z == 2) ? W2 : W3;
    unsigned short* T = (z == 0) ? T0 : (z == 1) ? T1 : (z == 2) ? T2 : T3;
    const int k0 = blockIdx.y * 64, n0 = blockIdx.x * 64;
    const int row = threadIdx.x >> 6, col = threadIdx.x & 63;
#pragma unroll
    for (int p = 0; p < 16; ++p)
        t[p * 4 + row][col] = W[(size_t)(k0 + p * 4 + row) * Dm + n0 + col];
    __syncthreads();
#pragma unroll
    for (int p = 0; p < 16; ++p)
        T[(size_t)(n0 + p * 4 + row) * Dm + k0 + col] = f2bf(t[col][p * 4 + row]);
}

// ---------------- m97-style bf16 MFMA GEMM mainloop (128x128) ----------------
__device__ __forceinline__ void gemm128_mainloop(const unsigned short* __restrict__ A,
                                                 const unsigned short* __restrict__ Bt,
                                                 int K, int m0, int n0,
                                                 unsigned short* As, unsigned short* Bs,
                                                 floatx4 acc[4][4]) {
    const int tid = threadIdx.x;
    const int lane = tid & 63, wave = tid >> 6;
    const int l15 = lane & 15, quad = lane >> 4;
    const int wm = (wave >> 1) * 64, wn = (wave & 1) * 64;

    for (int k0 = 0; k0 < K; k0 += 32) {
        __syncthreads();
#pragma unroll
        for (int c = 0; c < 2; ++c) {
            const int idx = c * 256 + tid;
            const int row = idx >> 2, kc = (idx & 3) * 8;
            lds16(&As[row * 32 + kc], A + (size_t)(m0 + row) * K + k0 + kc);
            lds16(&Bs[row * 32 + kc], Bt + (size_t)(n0 + row) * K + k0 + kc);
        }
        __syncthreads();
        bf16x8 af[4], bf[4];
#pragma unroll
        for (int i = 0; i < 4; ++i)
            af[i] = *(const bf16x8*)&As[(wm + i * 16 + l15) * 32 + quad * 8];
#pragma unroll
        for (int j = 0; j < 4; ++j)
            bf[j] = *(const bf16x8*)&Bs[(wn + j * 16 + l15) * 32 + quad * 8];
#pragma unroll
        for (int i = 0; i < 4; ++i)
#pragma unroll
            for (int j = 0; j < 4; ++j)
                acc[i][j] = __builtin_amdgcn_mfma_f32_16x16x32_bf16(af[i], bf[j], acc[i][j], 0, 0, 0);
    }
}

// QKV split over grid.z: z selects weight/output. Q scaled 0.125*log2e.
// z==2 (V) writes the transposed VbT [bh][d][tok] directly.
__global__ __launch_bounds__(256) void gemm_qkv(const unsigned short* __restrict__ xb,
                                                const unsigned short* __restrict__ Wqt,
                                                const unsigned short* __restrict__ Wkt,
                                                const unsigned short* __restrict__ Wvt,
                                                unsigned short* __restrict__ Qb,
                                                unsigned short* __restrict__ Kb,
                                                unsigned short* __restrict__ VbT) {
    __shared__ unsigned short As[128 * 32];
    __shared__ unsigned short Bs[128 * 32];
    const int z = blockIdx.z;
    const unsigned short* Bt = (z == 0) ? Wqt : (z == 1) ? Wkt : Wvt;
    const float scale = (z == 0) ? (0.125f * 1.4426950408889634f) : 1.0f;
    const int m0 = blockIdx.y * 128, n0 = blockIdx.x * 128;

    floatx4 acc[4][4];
#pragma unroll
    for (int i = 0; i < 4; ++i)
#pragma unroll
        for (int j = 0; j < 4; ++j) acc[i][j] = (floatx4){0.f, 0.f, 0.f, 0.f};

    gemm128_mainloop(xb, Bt, Dm, m0, n0, As, Bs, acc);

    const int lane = threadIdx.x & 63, wave = threadIdx.x >> 6;
    const int l15 = lane & 15, quad = lane >> 4;
    const int wm = (wave >> 1) * 64, wn = (wave & 1) * 64;

    if (z == 2) {
#pragma unroll
        for (int i = 0; i < 4; ++i)
#pragma unroll
            for (int j = 0; j < 4; ++j) {
                const int col = n0 + wn + j * 16 + l15;
                const int hh = col >> 6, dd = col & 63;
                const int tok = m0 + wm + i * 16 + quad * 4;
                const int bb = tok >> 11, tl = tok & (Tseq - 1);
                ushort4 o;
                o.x = f2bf(acc[i][j][0]); o.y = f2bf(acc[i][j][1]);
                o.z = f2bf(acc[i][j][2]); o.w = f2bf(acc[i][j][3]);
                *(ushort4*)&VbT[((size_t)((bb * NH + hh) * HD + dd)) * Tseq + tl] = o;
            }
        return;
    }
    unsigned short* C = (z == 0) ? Qb : Kb;
#pragma unroll
    for (int i = 0; i < 4; ++i)
#pragma unroll
        for (int j = 0; j < 4; ++j)
#pragma unroll
            for (int r = 0; r < 4; ++r) {
                const int row = m0 + wm + i * 16 + quad * 4 + r;
                const int col = n0 + wn + j * 16 + l15;
                C[(size_t)row * Dm + col] = f2bf(acc[i][j][r] * scale);
            }
}

// Final GEMM: Yb @ Wo -> fp32 out. 128(M)x64(N) tiles -> 512 blocks (2/CU).
__global__ __launch_bounds__(256) void gemm_out(const unsigned short* __restrict__ Yb,
                                                const unsigned short* __restrict__ Wot,
                                                float* __restrict__ out) {
    __shared__ unsigned short As[128 * 32];
    __shared__ unsigned short Bs[64 * 32];
    const int m0 = blockIdx.y * 128, n0 = blockIdx.x * 64;
    const int tid = threadIdx.x;
    const int lane = tid & 63, wave = tid >> 6;
    const int l15 = lane & 15, quad = lane >> 4;
    const int wm = (wave >> 1) * 64, wn = (wave & 1) * 32;

    floatx4 acc[4][2];
#pragma unroll
    for (int i = 0; i < 4; ++i)
#pragma unroll
        for (int j = 0; j < 2; ++j) acc[i][j] = (floatx4){0.f, 0.f, 0.f, 0.f};

    for (int k0 = 0; k0 < Dm; k0 += 32) {
        __syncthreads();
        {
#pragma unroll
            for (int c = 0; c < 2; ++c) {
                const int idx = c * 256 + tid;
                const int row = idx >> 2, kc = (idx & 3) * 8;
                lds16(&As[row * 32 + kc], Yb + (size_t)(m0 + row) * Dm + k0 + kc);
            }
            const int row = tid >> 2, kc = (tid & 3) * 8;
            lds16(&Bs[row * 32 + kc], Wot + (size_t)(n0 + row) * Dm + k0 + kc);
        }
        __syncthreads();
        bf16x8 af[4], bf[2];
#pragma unroll
        for (int i = 0; i < 4; ++i)
            af[i] = *(const bf16x8*)&As[(wm + i * 16 + l15) * 32 + quad * 8];
#pragma unroll
        for (int j = 0; j < 2; ++j)
            bf[j] = *(const bf16x8*)&Bs[(wn + j * 16 + l15) * 32 + quad * 8];
#pragma unroll
        for (int i = 0; i < 4; ++i)
#pragma unroll
            for (int j = 0; j < 2; ++j)
                acc[i][j] = __builtin_amdgcn_mfma_f32_16x16x32_bf16(af[i], bf[j], acc[i][j], 0, 0, 0);
    }

#pragma unroll
    for (int i = 0; i < 4; ++i)
#pragma unroll
        for (int j = 0; j < 2; ++j)
#pragma unroll
            for (int r = 0; r < 4; ++r) {
                const int row = m0 + wm + i * 16 + quad * 4 + r;
                const int col = n0 + wn + j * 16 + l15;
                out[(size_t)row * Dm + col] = acc[i][j][r];
            }
}

// ------------------------- bf16 MFMA causal flash attention -------------------
// grid (B*NH=32, 32). qt = 31 - blockIdx.y (longest blocks dispatch first).
// KT=128: two 64-key sub-tiles staged per barrier pair (half the barriers).
// 16 q/wave, 64B-row half-tiles, fixed-max exp2 softmax, l in epilogue.
__global__ __launch_bounds__(256) void attn_mfma(const unsigned short* __restrict__ Qb,
                                                 const unsigned short* __restrict__ Kb,
                                                 const unsigned short* __restrict__ VbT,
                                                 unsigned short* __restrict__ Yb) {
    const int bh = blockIdx.x;
    const int b = bh >> 4;
    const int h = bh & 15;
    const int qt = 31 - blockIdx.y;
    const int tid = threadIdx.x;
    const int wave = tid >> 6;
    const int lane = tid & 63;
    const int l15 = lane & 15;
    const int quad = lane >> 4;

    __shared__ unsigned short Ks0[2][64][32];  // [sub][key][d 0..31]
    __shared__ unsigned short Ks1[2][64][32];  // [sub][key][d 32..63]
    __shared__ unsigned short Vt0[2][64][32];  // [sub][d][key 0..31]
    __shared__ unsigned short Vt1[2][64][32];  // [sub][d][key 32..63]
    __shared__ unsigned short Ps[4][16][72];   // per-wave P transpose (16B rows)

    const size_t tok0 = (size_t)b * Tseq;
    const int colh = h * HD;
    const unsigned short* vbase = VbT + (size_t)bh * HD * Tseq;

    const int qrow = qt * 64 + wave * 16;

    const unsigned short* qptr = Qb + (tok0 + qrow + l15) * Dm + colh + quad * 8;
    const bf16x8 qf0 = *(const bf16x8*)(qptr);
    const bf16x8 qf1 = *(const bf16x8*)(qptr + 32);

    float l_lane[4] = {0.f, 0.f, 0.f, 0.f};
    floatx4 o_acc[4];
#pragma unroll
    for (int t = 0; t < 4; ++t) o_acc[t] = (floatx4){0.f, 0.f, 0.f, 0.f};

    const int srow = tid >> 2;
    const int sc8 = (tid & 3) * 8;

    const int niter = (qt + 2) >> 1;   // ceil((qt+1)/2), 64-key tiles in pairs
    for (int it = 0; it < niter; ++it) {
        const int k0 = it * 128;
        __syncthreads();
#pragma unroll
        for (int s = 0; s < 2; ++s) {
            const unsigned short* krow = Kb + (tok0 + k0 + s * 64 + srow) * Dm + colh;
            const unsigned short* vrow = vbase + (size_t)srow * Tseq + k0 + s * 64;
            lds16(&Ks0[s][srow][sc8], krow + sc8);
            lds16(&Ks1[s][srow][sc8], krow + 32 + sc8);
            lds16(&Vt0[s][srow][sc8], vrow + sc8);
            lds16(&Vt1[s][srow][sc8], vrow + 32 + sc8);
        }
        __syncthreads();

#pragma unroll
        for (int s = 0; s < 2; ++s) {
            const int k0s = k0 + s * 64;
            if (k0s > qrow + 15) continue;  // wave-uniform; no barriers inside

            floatx4 sf[4];
#pragma unroll
            for (int t = 0; t < 4; ++t) {
                floatx4 c = (floatx4){0.f, 0.f, 0.f, 0.f};
                const bf16x8 b0 = *(const bf16x8*)&Ks0[s][t * 16 + l15][quad * 8];
                const bf16x8 b1 = *(const bf16x8*)&Ks1[s][t * 16 + l15][quad * 8];
                c = __builtin_amdgcn_mfma_f32_16x16x32_bf16(qf0, b0, c, 0, 0, 0);
                c = __builtin_amdgcn_mfma_f32_16x16x32_bf16(qf1, b1, c, 0, 0, 0);
                sf[t] = c;
            }

            if (k0s + 63 > qrow) {  // diagonal sub-tile: causal mask
#pragma unroll
                for (int t = 0; t < 4; ++t)
#pragma unroll
                    for (int r = 0; r < 4; ++r) {
                        const int kl = k0s + t * 16 + l15;
                        const int ql = qrow + quad * 4 + r;
                        if (kl > ql) sf[t][r] = -1.0e30f;
                    }
            }

#pragma unroll
            for (int t = 0; t < 4; ++t)
#pragma unroll
                for (int r = 0; r < 4; ++r) {
                    const float p = __builtin_amdgcn_exp2f(sf[t][r]);
                    l_lane[r] += p;
                    Ps[wave][quad * 4 + r][t * 16 + l15] = f2bf_fast(p);
                }

            const bf16x8 pa0 = *(const bf16x8*)&Ps[wave][l15][quad * 8];
            const bf16x8 pa1 = *(const bf16x8*)&Ps[wave][l15][32 + quad * 8];
#pragma unroll
            for (int t = 0; t < 4; ++t) {
                const bf16x8 vb0 = *(const bf16x8*)&Vt0[s][t * 16 + l15][quad * 8];
                const bf16x8 vb1 = *(const bf16x8*)&Vt1[s][t * 16 + l15][quad * 8];
                o_acc[t] = __builtin_amdgcn_mfma_f32_16x16x32_bf16(pa0, vb0, o_acc[t], 0, 0, 0);
                o_acc[t] = __builtin_amdgcn_mfma_f32_16x16x32_bf16(pa1, vb1, o_acc[t], 0, 0, 0);
            }
        }
    }

#pragma unroll
    for (int off = 1; off < 16; off <<= 1)
#pragma unroll
        for (int r = 0; r < 4; ++r)
            l_lane[r] += __shfl_xor(l_lane[r], off);
    float inv_l[4];
#pragma unroll
    for (int r = 0; r < 4; ++r) inv_l[r] = 1.0f / l_lane[r];
#pragma unroll
    for (int t = 0; t < 4; ++t)
#pragma unroll
        for (int r = 0; r < 4; ++r) {
            const int q = qrow + quad * 4 + r;
            Yb[(tok0 + q) * Dm + colh + t * 16 + l15] = f2bf(o_acc[t][r] * inv_l[r]);
        }
}

// ------------------------------- launch --------------------------------------
extern "C" void kernel_launch(void* const* d_in, const int* in_sizes, int n_in,
                              void* d_out, int out_size, void* d_ws, size_t ws_size,
                              hipStream_t stream) {
    const float* x  = (const float*)d_in[0];
    const float* Wq = (const float*)d_in[1];
    const float* Wk = (const float*)d_in[2];
    const float* Wv = (const float*)d_in[3];
    const float* Wo = (const float*)d_in[4];
    float* out = (float*)d_out;

    const int M = Bsz * Tseq;  // 4096
    char* ws = (char*)d_ws;
    unsigned short* xb  = (unsigned short*)(ws);
    unsigned short* Wqt = (unsigned short*)(ws + (((size_t)8)  << 20));
    unsigned short* Wkt = (unsigned short*)(ws + (((size_t)10) << 20));
    unsigned short* Wvt = (unsigned short*)(ws + (((size_t)12) << 20));
    unsigned short* Wot = (unsigned short*)(ws + (((size_t)14) << 20));
    unsigned short* Qb  = (unsigned short*)(ws + (((size_t)16) << 20));
    unsigned short* Kb  = (unsigned short*)(ws + (((size_t)24) << 20));
    unsigned short* VbT = (unsigned short*)(ws + (((size_t)32) << 20));
    unsigned short* Yb  = (unsigned short*)(ws + (((size_t)40) << 20));

    dim3 blk(256);
    hipLaunchKernelGGL(prep, dim3(16, 16, 20), blk, 0, stream,
                       x, Wq, Wk, Wv, Wo, xb, Wqt, Wkt, Wvt, Wot);

    hipLaunchKernelGGL(gemm_qkv, dim3(Dm / 128, M / 128, 3), blk, 0, stream,
                       xb, Wqt, Wkt, Wvt, Qb, Kb, VbT);

    hipLaunchKernelGGL(attn_mfma, dim3(Bsz * NH, 32), blk, 0, stream, Qb, Kb, VbT, Yb);

    hipLaunchKernelGGL(gemm_out, dim3(Dm / 64, M / 128), blk, 0, stream, Yb, Wot, out);
}

// Round 13
// 169.736 us; speedup vs baseline: 1.1867x; 1.0231x over previous
//
#include <hip/hip_runtime.h>
#include <hip/hip_bf16.h>
#include <math.h>

// B=2, T=2048, D=1024, H=16, hd=64. fp32 in/out.
// Round 13: (1) attn computes S^T = K*Q^T by swapping MFMA operands (A/B
// frag lane-maps are identical) -> each lane holds 4 consecutive keys for
// one query: Ps stores become 4x ds_write_b64 (vs 16x conflicted b16),
// l-denominator is one scalar/lane. (2) gemm_out 64x64 tiles -> 1024 blocks
// (4/CU; blocks/CU>=3 rule). Rest as R12.
// ws (MB): xb@0[8] Wqt@8[2] Wkt@10[2] Wvt@12[2] Wot@14[2]
// Qb@16[8] Kb@24[8] VbT@32[8] Yb@40[8] = 48 MB.

#define Bsz  2
#define Tseq 2048
#define Dm   1024
#define NH   16
#define HD   64

typedef short bf16x8 __attribute__((ext_vector_type(8)));
typedef float floatx4 __attribute__((ext_vector_type(4)));

__device__ __forceinline__ unsigned short f2bf(float f) {
    __hip_bfloat16 h = __float2bfloat16(f);
    return *reinterpret_cast<unsigned short*>(&h);
}

// cheap bf16: round-half-up (max 0.5 ulp); 2 VALU ops
__device__ __forceinline__ unsigned short f2bf_fast(float f) {
    unsigned int u = __builtin_bit_cast(unsigned int, f);
    return (unsigned short)((u + 0x8000u) >> 16);
}

// async global->LDS, 16 B per lane. LDS dest must be waveBase + lane*16.
__device__ __forceinline__ void lds16(unsigned short* lds, const unsigned short* g) {
    __builtin_amdgcn_global_load_lds(
        (const __attribute__((address_space(1))) void*)g,
        (__attribute__((address_space(3))) void*)lds, 16, 0, 0);
}

// ---------------- prep: W transpose-cast (z<4) + x cast (z>=4) ---------------
__global__ __launch_bounds__(256) void prep(const float* __restrict__ x,
                                            const float* __restrict__ W0,
                                            const float* __restrict__ W1,
                                            const float* __restrict__ W2,
                                            const float* __restrict__ W3,
                                            unsigned short* __restrict__ xb,
                                            unsigned short* __restrict__ T0,
                                            unsigned short* __restrict__ T1,
                                            unsigned short* __restrict__ T2,
                                            unsigned short* __restrict__ T3) {
    __shared__ float t[64][65];
    const int z = blockIdx.z;
    if (z >= 4) {  // cast x
        const int bi = (z - 4) * 256 + blockIdx.y * 16 + blockIdx.x;
        const size_t i = (size_t)bi * 256 + threadIdx.x;
        const float4 v = ((const float4*)x)[i];
        ushort4 o;
        o.x = f2bf(v.x); o.y = f2bf(v.y); o.z = f2bf(v.z); o.w = f2bf(v.w);
        ((ushort4*)xb)[i] = o;
        return;
    }
    const float* W = (z == 0) ? W0 : (z == 1) ? W1 : (z == 2) ? W2 : W3;
    unsigned short* T = (z == 0) ? T0 : (z == 1) ? T1 : (z == 2) ? T2 : T3;
    const int k0 = blockIdx.y * 64, n0 = blockIdx.x * 64;
    const int row = threadIdx.x >> 6, col = threadIdx.x & 63;
#pragma unroll
    for (int p = 0; p < 16; ++p)
        t[p * 4 + row][col] = W[(size_t)(k0 + p * 4 + row) * Dm + n0 + col];
    __syncthreads();
#pragma unroll
    for (int p = 0; p < 16; ++p)
        T[(size_t)(n0 + p * 4 + row) * Dm + k0 + col] = f2bf(t[col][p * 4 + row]);
}

// ---------------- m97-style bf16 MFMA GEMM mainloop (128x128) ----------------
__device__ __forceinline__ void gemm128_mainloop(const unsigned short* __restrict__ A,
                                                 const unsigned short* __restrict__ Bt,
                                                 int K, int m0, int n0,
                                                 unsigned short* As, unsigned short* Bs,
                                                 floatx4 acc[4][4]) {
    const int tid = threadIdx.x;
    const int lane = tid & 63, wave = tid >> 6;
    const int l15 = lane & 15, quad = lane >> 4;
    const int wm = (wave >> 1) * 64, wn = (wave & 1) * 64;

    for (int k0 = 0; k0 < K; k0 += 32) {
        __syncthreads();
#pragma unroll
        for (int c = 0; c < 2; ++c) {
            const int idx = c * 256 + tid;
            const int row = idx >> 2, kc = (idx & 3) * 8;
            lds16(&As[row * 32 + kc], A + (size_t)(m0 + row) * K + k0 + kc);
            lds16(&Bs[row * 32 + kc], Bt + (size_t)(n0 + row) * K + k0 + kc);
        }
        __syncthreads();
        bf16x8 af[4], bf[4];
#pragma unroll
        for (int i = 0; i < 4; ++i)
            af[i] = *(const bf16x8*)&As[(wm + i * 16 + l15) * 32 + quad * 8];
#pragma unroll
        for (int j = 0; j < 4; ++j)
            bf[j] = *(const bf16x8*)&Bs[(wn + j * 16 + l15) * 32 + quad * 8];
#pragma unroll
        for (int i = 0; i < 4; ++i)
#pragma unroll
            for (int j = 0; j < 4; ++j)
                acc[i][j] = __builtin_amdgcn_mfma_f32_16x16x32_bf16(af[i], bf[j], acc[i][j], 0, 0, 0);
    }
}

// QKV split over grid.z: z selects weight/output. Q scaled 0.125*log2e.
// z==2 (V) writes the transposed VbT [bh][d][tok] directly.
__global__ __launch_bounds__(256) void gemm_qkv(const unsigned short* __restrict__ xb,
                                                const unsigned short* __restrict__ Wqt,
                                                const unsigned short* __restrict__ Wkt,
                                                const unsigned short* __restrict__ Wvt,
                                                unsigned short* __restrict__ Qb,
                                                unsigned short* __restrict__ Kb,
                                                unsigned short* __restrict__ VbT) {
    __shared__ unsigned short As[128 * 32];
    __shared__ unsigned short Bs[128 * 32];
    const int z = blockIdx.z;
    const unsigned short* Bt = (z == 0) ? Wqt : (z == 1) ? Wkt : Wvt;
    const float scale = (z == 0) ? (0.125f * 1.4426950408889634f) : 1.0f;
    const int m0 = blockIdx.y * 128, n0 = blockIdx.x * 128;

    floatx4 acc[4][4];
#pragma unroll
    for (int i = 0; i < 4; ++i)
#pragma unroll
        for (int j = 0; j < 4; ++j) acc[i][j] = (floatx4){0.f, 0.f, 0.f, 0.f};

    gemm128_mainloop(xb, Bt, Dm, m0, n0, As, Bs, acc);

    const int lane = threadIdx.x & 63, wave = threadIdx.x >> 6;
    const int l15 = lane & 15, quad = lane >> 4;
    const int wm = (wave >> 1) * 64, wn = (wave & 1) * 64;

    if (z == 2) {
#pragma unroll
        for (int i = 0; i < 4; ++i)
#pragma unroll
            for (int j = 0; j < 4; ++j) {
                const int col = n0 + wn + j * 16 + l15;
                const int hh = col >> 6, dd = col & 63;
                const int tok = m0 + wm + i * 16 + quad * 4;
                const int bb = tok >> 11, tl = tok & (Tseq - 1);
                ushort4 o;
                o.x = f2bf(acc[i][j][0]); o.y = f2bf(acc[i][j][1]);
                o.z = f2bf(acc[i][j][2]); o.w = f2bf(acc[i][j][3]);
                *(ushort4*)&VbT[((size_t)((bb * NH + hh) * HD + dd)) * Tseq + tl] = o;
            }
        return;
    }
    unsigned short* C = (z == 0) ? Qb : Kb;
#pragma unroll
    for (int i = 0; i < 4; ++i)
#pragma unroll
        for (int j = 0; j < 4; ++j)
#pragma unroll
            for (int r = 0; r < 4; ++r) {
                const int row = m0 + wm + i * 16 + quad * 4 + r;
                const int col = n0 + wn + j * 16 + l15;
                C[(size_t)row * Dm + col] = f2bf(acc[i][j][r] * scale);
            }
}

// Final GEMM: Yb @ Wo -> fp32 out. 64x64 tiles -> 1024 blocks (4/CU).
__global__ __launch_bounds__(256) void gemm_out(const unsigned short* __restrict__ Yb,
                                                const unsigned short* __restrict__ Wot,
                                                float* __restrict__ out) {
    __shared__ unsigned short As[64 * 32];
    __shared__ unsigned short Bs[64 * 32];
    const int m0 = blockIdx.y * 64, n0 = blockIdx.x * 64;
    const int tid = threadIdx.x;
    const int lane = tid & 63, wave = tid >> 6;
    const int l15 = lane & 15, quad = lane >> 4;
    const int wm = (wave >> 1) * 32, wn = (wave & 1) * 32;

    floatx4 acc[2][2];
#pragma unroll
    for (int i = 0; i < 2; ++i)
#pragma unroll
        for (int j = 0; j < 2; ++j) acc[i][j] = (floatx4){0.f, 0.f, 0.f, 0.f};

    const int srow = tid >> 2, kc = (tid & 3) * 8;

    for (int k0 = 0; k0 < Dm; k0 += 32) {
        __syncthreads();
        lds16(&As[srow * 32 + kc], Yb + (size_t)(m0 + srow) * Dm + k0 + kc);
        lds16(&Bs[srow * 32 + kc], Wot + (size_t)(n0 + srow) * Dm + k0 + kc);
        __syncthreads();
        bf16x8 af[2], bf[2];
#pragma unroll
        for (int i = 0; i < 2; ++i)
            af[i] = *(const bf16x8*)&As[(wm + i * 16 + l15) * 32 + quad * 8];
#pragma unroll
        for (int j = 0; j < 2; ++j)
            bf[j] = *(const bf16x8*)&Bs[(wn + j * 16 + l15) * 32 + quad * 8];
#pragma unroll
        for (int i = 0; i < 2; ++i)
#pragma unroll
            for (int j = 0; j < 2; ++j)
                acc[i][j] = __builtin_amdgcn_mfma_f32_16x16x32_bf16(af[i], bf[j], acc[i][j], 0, 0, 0);
    }

#pragma unroll
    for (int i = 0; i < 2; ++i)
#pragma unroll
        for (int j = 0; j < 2; ++j)
#pragma unroll
            for (int r = 0; r < 4; ++r) {
                const int row = m0 + wm + i * 16 + quad * 4 + r;
                const int col = n0 + wn + j * 16 + l15;
                out[(size_t)row * Dm + col] = acc[i][j][r];
            }
}

// ------------------------- bf16 MFMA causal flash attention -------------------
// grid (B*NH=32, 32). qt = 31 - blockIdx.y (longest blocks dispatch first).
// KT=128 (two 64-key sub-tiles per barrier pair). QK^T computed as
// S^T = K*Q^T (swapped MFMA operands): lane holds 4 consecutive keys for
// query l15 -> Ps written as ushort4 b64 (2-way aliased, ~free), l is one
// scalar/lane reduced with 2 shuffles. 16 q/wave, fixed-max exp2 softmax.
__global__ __launch_bounds__(256) void attn_mfma(const unsigned short* __restrict__ Qb,
                                                 const unsigned short* __restrict__ Kb,
                                                 const unsigned short* __restrict__ VbT,
                                                 unsigned short* __restrict__ Yb) {
    const int bh = blockIdx.x;
    const int b = bh >> 4;
    const int h = bh & 15;
    const int qt = 31 - blockIdx.y;
    const int tid = threadIdx.x;
    const int wave = tid >> 6;
    const int lane = tid & 63;
    const int l15 = lane & 15;
    const int quad = lane >> 4;

    __shared__ unsigned short Ks0[2][64][32];  // [sub][key][d 0..31]
    __shared__ unsigned short Ks1[2][64][32];  // [sub][key][d 32..63]
    __shared__ unsigned short Vt0[2][64][32];  // [sub][d][key 0..31]
    __shared__ unsigned short Vt1[2][64][32];  // [sub][d][key 32..63]
    __shared__ unsigned short Ps[4][16][72];   // per-wave P [query][key]

    const size_t tok0 = (size_t)b * Tseq;
    const int colh = h * HD;
    const unsigned short* vbase = VbT + (size_t)bh * HD * Tseq;

    const int qrow = qt * 64 + wave * 16;

    const unsigned short* qptr = Qb + (tok0 + qrow + l15) * Dm + colh + quad * 8;
    const bf16x8 qf0 = *(const bf16x8*)(qptr);
    const bf16x8 qf1 = *(const bf16x8*)(qptr + 32);

    float l_lane = 0.f;                        // denom for query l15
    floatx4 o_acc[4];
#pragma unroll
    for (int t = 0; t < 4; ++t) o_acc[t] = (floatx4){0.f, 0.f, 0.f, 0.f};

    const int srow = tid >> 2;
    const int sc8 = (tid & 3) * 8;

    const int niter = (qt + 2) >> 1;   // ceil((qt+1)/2)
    for (int it = 0; it < niter; ++it) {
        const int k0 = it * 128;
        __syncthreads();
#pragma unroll
        for (int s = 0; s < 2; ++s) {
            const unsigned short* krow = Kb + (tok0 + k0 + s * 64 + srow) * Dm + colh;
            const unsigned short* vrow = vbase + (size_t)srow * Tseq + k0 + s * 64;
            lds16(&Ks0[s][srow][sc8], krow + sc8);
            lds16(&Ks1[s][srow][sc8], krow + 32 + sc8);
            lds16(&Vt0[s][srow][sc8], vrow + sc8);
            lds16(&Vt1[s][srow][sc8], vrow + 32 + sc8);
        }
        __syncthreads();

#pragma unroll
        for (int s = 0; s < 2; ++s) {
            const int k0s = k0 + s * 64;
            if (k0s > qrow + 15) continue;  // wave-uniform; no barriers inside

            // ---- S^T (64 keys x 16 queries): A=K frag, B=Q frag
            floatx4 sf[4];
#pragma unroll
            for (int t = 0; t < 4; ++t) {
                floatx4 c = (floatx4){0.f, 0.f, 0.f, 0.f};
                const bf16x8 kb0 = *(const bf16x8*)&Ks0[s][t * 16 + l15][quad * 8];
                const bf16x8 kb1 = *(const bf16x8*)&Ks1[s][t * 16 + l15][quad * 8];
                c = __builtin_amdgcn_mfma_f32_16x16x32_bf16(kb0, qf0, c, 0, 0, 0);
                c = __builtin_amdgcn_mfma_f32_16x16x32_bf16(kb1, qf1, c, 0, 0, 0);
                sf[t] = c;   // row = key = t*16 + quad*4 + r, col = query = l15
            }

            // ---- causal mask (diagonal sub-tile): key > query
            if (k0s + 63 > qrow) {
                const int ql = qrow + l15;
#pragma unroll
                for (int t = 0; t < 4; ++t)
#pragma unroll
                    for (int r = 0; r < 4; ++r) {
                        const int kl = k0s + t * 16 + quad * 4 + r;
                        if (kl > ql) sf[t][r] = -1.0e30f;
                    }
            }

            // ---- p = exp2(s); l (scalar) accumulate; Ps b64 stores
#pragma unroll
            for (int t = 0; t < 4; ++t) {
                float p0 = __builtin_amdgcn_exp2f(sf[t][0]);
                float p1 = __builtin_amdgcn_exp2f(sf[t][1]);
                float p2 = __builtin_amdgcn_exp2f(sf[t][2]);
                float p3 = __builtin_amdgcn_exp2f(sf[t][3]);
                l_lane += (p0 + p1) + (p2 + p3);
                ushort4 o;
                o.x = f2bf_fast(p0); o.y = f2bf_fast(p1);
                o.z = f2bf_fast(p2); o.w = f2bf_fast(p3);
                *(ushort4*)&Ps[wave][l15][t * 16 + quad * 4] = o;
            }

            // ---- PV: O (16 x 64) += P (16 x 64) @ V (64 x 64)
            const bf16x8 pa0 = *(const bf16x8*)&Ps[wave][l15][quad * 8];
            const bf16x8 pa1 = *(const bf16x8*)&Ps[wave][l15][32 + quad * 8];
#pragma unroll
            for (int t = 0; t < 4; ++t) {
                const bf16x8 vb0 = *(const bf16x8*)&Vt0[s][t * 16 + l15][quad * 8];
                const bf16x8 vb1 = *(const bf16x8*)&Vt1[s][t * 16 + l15][quad * 8];
                o_acc[t] = __builtin_amdgcn_mfma_f32_16x16x32_bf16(pa0, vb0, o_acc[t], 0, 0, 0);
                o_acc[t] = __builtin_amdgcn_mfma_f32_16x16x32_bf16(pa1, vb1, o_acc[t], 0, 0, 0);
            }
        }
    }

    // ---- epilogue: reduce l across the 4 quads (same l15), redistribute,
    // then Y = O / l. o_acc row = query quad*4+r, col = d = l15.
    l_lane += __shfl_xor(l_lane, 16);
    l_lane += __shfl_xor(l_lane, 32);
    const float inv_q = 1.0f / l_lane;         // inv denom for query l15
    float inv_r[4];
#pragma unroll
    for (int r = 0; r < 4; ++r)
        inv_r[r] = __shfl(inv_q, (lane & 48) | (quad * 4 + r));
#pragma unroll
    for (int t = 0; t < 4; ++t)
#pragma unroll
        for (int r = 0; r < 4; ++r) {
            const int q = qrow + quad * 4 + r;
            Yb[(tok0 + q) * Dm + colh + t * 16 + l15] = f2bf(o_acc[t][r] * inv_r[r]);
        }
}

// ------------------------------- launch --------------------------------------
extern "C" void kernel_launch(void* const* d_in, const int* in_sizes, int n_in,
                              void* d_out, int out_size, void* d_ws, size_t ws_size,
                              hipStream_t stream) {
    const float* x  = (const float*)d_in[0];
    const float* Wq = (const float*)d_in[1];
    const float* Wk = (const float*)d_in[2];
    const float* Wv = (const float*)d_in[3];
    const float* Wo = (const float*)d_in[4];
    float* out = (float*)d_out;

    const int M = Bsz * Tseq;  // 4096
    char* ws = (char*)d_ws;
    unsigned short* xb  = (unsigned short*)(ws);
    unsigned short* Wqt = (unsigned short*)(ws + (((size_t)8)  << 20));
    unsigned short* Wkt = (unsigned short*)(ws + (((size_t)10) << 20));
    unsigned short* Wvt = (unsigned short*)(ws + (((size_t)12) << 20));
    unsigned short* Wot = (unsigned short*)(ws + (((size_t)14) << 20));
    unsigned short* Qb  = (unsigned short*)(ws + (((size_t)16) << 20));
    unsigned short* Kb  = (unsigned short*)(ws + (((size_t)24) << 20));
    unsigned short* VbT = (unsigned short*)(ws + (((size_t)32) << 20));
    unsigned short* Yb  = (unsigned short*)(ws + (((size_t)40) << 20));

    dim3 blk(256);
    hipLaunchKernelGGL(prep, dim3(16, 16, 20), blk, 0, stream,
                       x, Wq, Wk, Wv, Wo, xb, Wqt, Wkt, Wvt, Wot);

    hipLaunchKernelGGL(gemm_qkv, dim3(Dm / 128, M / 128, 3), blk, 0, stream,
                       xb, Wqt, Wkt, Wvt, Qb, Kb, VbT);

    hipLaunchKernelGGL(attn_mfma, dim3(Bsz * NH, 32), blk, 0, stream, Qb, Kb, VbT, Yb);

    hipLaunchKernelGGL(gemm_out, dim3(Dm / 64, M / 64), blk, 0, stream, Yb, Wot, out);
}